// Round 6
// baseline (421.215 us; speedup 1.0000x reference)
//
#include <hip/hip_runtime.h>
#include <hip/hip_bf16.h>

typedef __bf16 bf16x8 __attribute__((ext_vector_type(8)));
typedef float  f32x4  __attribute__((ext_vector_type(4)));

#define EDGES_TOTAL 1000000
#define TILE_E 16
#define TILES (EDGES_TOTAL / TILE_E)      // 62500 tiles of 16 edges
#define EMB_ELEMS 64000000ULL             // 500000*128
#define EMB_CHUNKS (EMB_ELEMS / 8)
#define GRID_BLOCKS 1280                  // gather grid
#define CHUNK ((TILES + GRID_BLOCKS - 1) / GRID_BLOCKS)   // 49 tiles/block, chunked

#define NB 1024                           // si-buckets (si>>9, max id 976)
#define BSHIFT 9
#define SORT_BLOCKS ((EDGES_TOTAL + 1023) / 1024)         // 977, 4 edges/thread

// ws layout (bytes)
#define OFF_EMBB   0ULL
#define OFF_COUNTS (EMB_ELEMS * 2ULL)                     // 128,000,000
#define OFF_CURSOR (OFF_COUNTS + NB * 4ULL)
#define OFF_EIDX   (OFF_CURSOR + NB * 4ULL)
#define WS_NEED_B  (OFF_EIDX + EDGES_TOTAL * 4ULL)        // ~132.0 MB
#define WS_NEED_A  (EMB_ELEMS * 2ULL)                     // 128 MB (unbucketed path)

__device__ __forceinline__ bf16x8 load_cvt8(const float* __restrict__ p) {
    f32x4 a = *(const f32x4*)p;
    f32x4 b = *(const f32x4*)(p + 4);
    bf16x8 r;
    r[0] = (__bf16)a[0]; r[1] = (__bf16)a[1]; r[2] = (__bf16)a[2]; r[3] = (__bf16)a[3];
    r[4] = (__bf16)b[0]; r[5] = (__bf16)b[1]; r[6] = (__bf16)b[2]; r[7] = (__bf16)b[3];
    return r;
}

__device__ __forceinline__ void gload_lds16(const void* g, void* l) {
    __builtin_amdgcn_global_load_lds(
        (const __attribute__((address_space(1))) void*)g,
        (__attribute__((address_space(3))) void*)l, 16, 0, 0);
}

// ---------- Phase 0: emb f32 -> bf16 in ws ----------
__global__ __launch_bounds__(256) void cvt_bf16(
    const float* __restrict__ emb, __bf16* __restrict__ dst)
{
    const size_t stride = (size_t)gridDim.x * blockDim.x;
    for (size_t i = (size_t)blockIdx.x * blockDim.x + threadIdx.x; i < EMB_CHUNKS; i += stride) {
        size_t e = i * 8;
        *(bf16x8*)(dst + e) = load_cvt8(emb + e);
    }
}

// ---------- Sort phase: bucket edges by si>>9 ----------
__global__ __launch_bounds__(256) void zero_counts(unsigned* __restrict__ counts) {
    for (int i = threadIdx.x; i < NB; i += 256) counts[i] = 0;
}

__global__ __launch_bounds__(256) void hist_kernel(
    const int* __restrict__ si, unsigned* __restrict__ counts)
{
    __shared__ unsigned lc[NB];
    const int tid = threadIdx.x;
    for (int i = tid; i < NB; i += 256) lc[i] = 0;
    __syncthreads();
    const int base = blockIdx.x * 1024;
    #pragma unroll
    for (int k = 0; k < 4; ++k) {
        int e = base + k * 256 + tid;
        if (e < EDGES_TOTAL) atomicAdd(&lc[((unsigned)si[e]) >> BSHIFT], 1u);
    }
    __syncthreads();
    for (int i = tid; i < NB; i += 256)
        if (lc[i]) atomicAdd(&counts[i], lc[i]);
}

__global__ __launch_bounds__(256) void scan_kernel(
    unsigned* __restrict__ counts, unsigned* __restrict__ cursor)
{
    __shared__ unsigned ps[256];
    const int t = threadIdx.x;
    unsigned v[4], sum = 0;
    #pragma unroll
    for (int k = 0; k < 4; ++k) { v[k] = counts[t * 4 + k]; sum += v[k]; }
    ps[t] = sum;
    __syncthreads();
    for (int off = 1; off < 256; off <<= 1) {
        unsigned x = (t >= off) ? ps[t - off] : 0u;
        __syncthreads();
        ps[t] += x;
        __syncthreads();
    }
    unsigned ex = t ? ps[t - 1] : 0u;
    #pragma unroll
    for (int k = 0; k < 4; ++k) {
        unsigned c = v[k];
        counts[t * 4 + k] = ex;
        cursor[t * 4 + k] = ex;
        ex += c;
    }
}

__global__ __launch_bounds__(256) void scatter_kernel(
    const int* __restrict__ si, unsigned* __restrict__ cursor, unsigned* __restrict__ eidx)
{
    __shared__ unsigned lc[NB];
    const int tid = threadIdx.x;
    for (int i = tid; i < NB; i += 256) lc[i] = 0;
    __syncthreads();
    const int base = blockIdx.x * 1024;
    int b[4];
    #pragma unroll
    for (int k = 0; k < 4; ++k) {
        int e = base + k * 256 + tid;
        b[k] = -1;
        if (e < EDGES_TOTAL) { b[k] = (int)(((unsigned)si[e]) >> BSHIFT); atomicAdd(&lc[b[k]], 1u); }
    }
    __syncthreads();
    // reserve a global range per nonzero bucket; lc[i] becomes this block's cursor
    for (int i = tid; i < NB; i += 256) {
        unsigned c = lc[i];
        if (c) lc[i] = atomicAdd(&cursor[i], c);
    }
    __syncthreads();
    #pragma unroll
    for (int k = 0; k < 4; ++k) {
        int e = base + k * 256 + tid;
        if (e < EDGES_TOTAL) {
            unsigned pos = atomicAdd(&lc[b[k]], 1u);
            eidx[pos] = (unsigned)e;
        }
    }
}

// ---------- Phase 1 (bucketed): staged gather + MFMA over permuted edges ----------
// Chunked tile->block mapping keeps each si-bucket's edges on ONE CU so the
// ~2x duplicate si-rows hit L1/L2 instead of re-requesting random L3 lines.
__global__ __launch_bounds__(256, 5) void sampleall_bucketed(
    const __bf16* __restrict__ embb, const float* __restrict__ rel,
    const float* __restrict__ tokeys, const float* __restrict__ toqueries,
    const int* __restrict__ si, const int* __restrict__ pi, const int* __restrict__ oi,
    const unsigned* __restrict__ eidx, float* __restrict__ out)
{
    __shared__ __align__(16) __bf16 stage[2][32 * 128];   // rows 0-15 = si, 16-31 = oi
    __shared__ float red[4][16];

    const int tid  = threadIdx.x;
    const int lane = tid & 63;
    const int wid  = tid >> 6;
    const int c    = lane & 15;
    const int g    = lane >> 4;
    const int sub  = tid >> 4;     // 0..15
    const int gr   = tid & 15;     // 16B granule in row

    bf16x8 wk[2][4], wq[2][4];
    #pragma unroll
    for (int tl = 0; tl < 2; ++tl) {
        const int row = (wid * 2 + tl) * 16 + c;
        #pragma unroll
        for (int j0 = 0; j0 < 4; ++j0) {
            wk[tl][j0] = load_cvt8(tokeys    + row * 128 + j0 * 32 + g * 8);
            wq[tl][j0] = load_cvt8(toqueries + row * 128 + j0 * 32 + g * 8);
        }
    }

    auto stage_issue = [&](int e0, int buf) {
        const int ed = (int)eidx[e0 + sub];
        #pragma unroll
        for (int k = 0; k < 2; ++k) {
            const int r   = k * 16 + sub;
            const int idx = k ? oi[ed] : si[ed];
            const __bf16* src = embb + (size_t)idx * 128 + (gr ^ (r & 7)) * 8;
            __bf16* dst = &stage[buf][(k * 16 + (sub & ~3)) * 128];  // wave-uniform
            gload_lds16(src, dst);
        }
    };

    auto rdfrag = [&](int buf, int p, int j0) -> bf16x8 {
        const char* base = (const char*)&stage[buf][0];
        const int off = p * 256 + ((j0 * 64 + g * 16) ^ ((p & 7) << 4));
        return *(const bf16x8*)(base + off);
    };

    const int t0 = (int)blockIdx.x * CHUNK;
    const int t1 = (t0 + CHUNK < TILES) ? t0 + CHUNK : TILES;
    if (t0 >= t1) return;

    stage_issue(t0 * TILE_E, 0);
    __syncthreads();

    int b = 0;
    for (int tile = t0; tile < t1; ++tile) {
        if (tile + 1 < t1) stage_issue((tile + 1) * TILE_E, b ^ 1);

        const int e0 = tile * TILE_E;
        f32x4 aK[2], aQ[2];
        #pragma unroll
        for (int tl = 0; tl < 2; ++tl) {
            aK[tl] = (f32x4){0.f, 0.f, 0.f, 0.f};
            aQ[tl] = (f32x4){0.f, 0.f, 0.f, 0.f};
        }

        #pragma unroll
        for (int j0 = 0; j0 < 4; ++j0) {
            bf16x8 bs = rdfrag(b, c,      j0);
            bf16x8 bo = rdfrag(b, 16 + c, j0);
            #pragma unroll
            for (int tl = 0; tl < 2; ++tl) {
                aK[tl] = __builtin_amdgcn_mfma_f32_16x16x32_bf16(wk[tl][j0], bs, aK[tl], 0, 0, 0);
                aQ[tl] = __builtin_amdgcn_mfma_f32_16x16x32_bf16(wq[tl][j0], bo, aQ[tl], 0, 0, 0);
            }
        }

        const int edc = (int)eidx[e0 + c];
        const int pA  = pi[edc];
        float d0 = 0.f;
        #pragma unroll
        for (int tl = 0; tl < 2; ++tl) {
            f32x4 rA = *(const f32x4*)(rel + (size_t)pA * 128 + (wid * 2 + tl) * 16 + g * 4);
            #pragma unroll
            for (int r = 0; r < 4; ++r)
                d0 += aK[tl][r] * aQ[tl][r] * rA[r];
        }
        d0 += __shfl_xor(d0, 16); d0 += __shfl_xor(d0, 32);
        if (lane < 16) red[wid][c] = d0;

        __syncthreads();
        if (tid < 16) {
            const float s = red[0][tid] + red[1][tid] + red[2][tid] + red[3][tid];
            out[eidx[e0 + tid]] = s * 0.08838834764831845f;   // 1/sqrt(128)
        }
        __syncthreads();
        b ^= 1;
    }
}

// ---------- Phase 1 (unbucketed fallback, R5) ----------
__global__ __launch_bounds__(256, 5) void sampleall_staged(
    const __bf16* __restrict__ embb, const float* __restrict__ rel,
    const float* __restrict__ tokeys, const float* __restrict__ toqueries,
    const int* __restrict__ si, const int* __restrict__ pi, const int* __restrict__ oi,
    float* __restrict__ out)
{
    __shared__ __align__(16) __bf16 stage[2][32 * 128];
    __shared__ float red[4][16];

    const int tid  = threadIdx.x;
    const int lane = tid & 63;
    const int wid  = tid >> 6;
    const int c    = lane & 15;
    const int g    = lane >> 4;
    const int sub  = tid >> 4;
    const int gr   = tid & 15;

    bf16x8 wk[2][4], wq[2][4];
    #pragma unroll
    for (int tl = 0; tl < 2; ++tl) {
        const int row = (wid * 2 + tl) * 16 + c;
        #pragma unroll
        for (int j0 = 0; j0 < 4; ++j0) {
            wk[tl][j0] = load_cvt8(tokeys    + row * 128 + j0 * 32 + g * 8);
            wq[tl][j0] = load_cvt8(toqueries + row * 128 + j0 * 32 + g * 8);
        }
    }

    auto stage_issue = [&](int e0, int buf) {
        #pragma unroll
        for (int k = 0; k < 2; ++k) {
            const int r   = k * 16 + sub;
            const int idx = k ? oi[e0 + sub] : si[e0 + sub];
            const __bf16* src = embb + (size_t)idx * 128 + (gr ^ (r & 7)) * 8;
            __bf16* dst = &stage[buf][(k * 16 + (sub & ~3)) * 128];
            gload_lds16(src, dst);
        }
    };

    auto rdfrag = [&](int buf, int p, int j0) -> bf16x8 {
        const char* base = (const char*)&stage[buf][0];
        const int off = p * 256 + ((j0 * 64 + g * 16) ^ ((p & 7) << 4));
        return *(const bf16x8*)(base + off);
    };

    int tile = (int)blockIdx.x;
    stage_issue(tile * TILE_E, 0);
    __syncthreads();

    int b = 0;
    for (; tile < TILES; tile += GRID_BLOCKS) {
        const int nt = tile + GRID_BLOCKS;
        if (nt < TILES) stage_issue(nt * TILE_E, b ^ 1);

        const int e0 = tile * TILE_E;
        f32x4 aK[2], aQ[2];
        #pragma unroll
        for (int tl = 0; tl < 2; ++tl) {
            aK[tl] = (f32x4){0.f, 0.f, 0.f, 0.f};
            aQ[tl] = (f32x4){0.f, 0.f, 0.f, 0.f};
        }
        #pragma unroll
        for (int j0 = 0; j0 < 4; ++j0) {
            bf16x8 bs = rdfrag(b, c,      j0);
            bf16x8 bo = rdfrag(b, 16 + c, j0);
            #pragma unroll
            for (int tl = 0; tl < 2; ++tl) {
                aK[tl] = __builtin_amdgcn_mfma_f32_16x16x32_bf16(wk[tl][j0], bs, aK[tl], 0, 0, 0);
                aQ[tl] = __builtin_amdgcn_mfma_f32_16x16x32_bf16(wq[tl][j0], bo, aQ[tl], 0, 0, 0);
            }
        }
        const int pA = pi[e0 + c];
        float d0 = 0.f;
        #pragma unroll
        for (int tl = 0; tl < 2; ++tl) {
            f32x4 rA = *(const f32x4*)(rel + (size_t)pA * 128 + (wid * 2 + tl) * 16 + g * 4);
            #pragma unroll
            for (int r = 0; r < 4; ++r)
                d0 += aK[tl][r] * aQ[tl][r] * rA[r];
        }
        d0 += __shfl_xor(d0, 16); d0 += __shfl_xor(d0, 32);
        if (lane < 16) red[wid][c] = d0;

        __syncthreads();
        if (tid < 16) {
            const float s = red[0][tid] + red[1][tid] + red[2][tid] + red[3][tid];
            out[e0 + tid] = s * 0.08838834764831845f;
        }
        __syncthreads();
        b ^= 1;
    }
}

// ---------- Last-resort fallback (no ws): R1-style f32 gathers ----------
__global__ __launch_bounds__(256, 2) void sampleall_fused_f32(
    const float* __restrict__ emb, const float* __restrict__ rel,
    const float* __restrict__ tokeys, const float* __restrict__ toqueries,
    const int* __restrict__ si, const int* __restrict__ pi, const int* __restrict__ oi,
    float* __restrict__ out)
{
    __shared__ __align__(16) __bf16 ldsW[2][128 * 128];
    const int tid = threadIdx.x;
    #pragma unroll
    for (int it = 0; it < 16; ++it) {
        int gidx = tid + it * 256;
        int m    = gidx >> 11;
        int rm   = gidx & 2047;
        int row  = rm >> 4;
        int ch   = rm & 15;
        const float* src = (m ? toqueries : tokeys) + row * 128 + ch * 8;
        bf16x8 bv = load_cvt8(src);
        int byteoff = row * 256 + ((ch * 16) ^ ((row & 7) << 4));
        *(bf16x8*)((char*)(&ldsW[m][0]) + byteoff) = bv;
    }
    __syncthreads();

    const int lane = tid & 63;
    const int wid  = tid >> 6;
    const int c    = lane & 15;
    const int g    = lane >> 4;
    const int xm   = (c & 7) << 4;
    const char* wkbase = (const char*)(&ldsW[0][0]) + c * 256;
    const char* wqbase = (const char*)(&ldsW[1][0]) + c * 256;

    const int wtotal = (int)gridDim.x * 4;
    for (int tile = (int)blockIdx.x * 4 + wid; tile < EDGES_TOTAL / 32; tile += wtotal) {
        const int e0 = tile * 32;
        const int sA = si[e0 + c], sB = si[e0 + 16 + c];
        const int oA = oi[e0 + c], oB = oi[e0 + 16 + c];
        const int pA = pi[e0 + c], pB = pi[e0 + 16 + c];
        const float* ps0 = emb + (size_t)sA * 128 + g * 8;
        const float* ps1 = emb + (size_t)sB * 128 + g * 8;
        const float* po0 = emb + (size_t)oA * 128 + g * 8;
        const float* po1 = emb + (size_t)oB * 128 + g * 8;

        f32x4 accK0[8], accK1[8], accQ0[8], accQ1[8];
        #pragma unroll
        for (int t = 0; t < 8; ++t) {
            accK0[t] = (f32x4){0.f, 0.f, 0.f, 0.f};
            accK1[t] = (f32x4){0.f, 0.f, 0.f, 0.f};
            accQ0[t] = (f32x4){0.f, 0.f, 0.f, 0.f};
            accQ1[t] = (f32x4){0.f, 0.f, 0.f, 0.f};
        }
        #pragma unroll
        for (int j0 = 0; j0 < 4; ++j0) {
            bf16x8 bs0 = load_cvt8(ps0 + j0 * 32);
            bf16x8 bs1 = load_cvt8(ps1 + j0 * 32);
            bf16x8 bo0 = load_cvt8(po0 + j0 * 32);
            bf16x8 bo1 = load_cvt8(po1 + j0 * 32);
            const int offj = ((j0 * 64 + g * 16) ^ xm);
            #pragma unroll
            for (int t = 0; t < 8; ++t) {
                bf16x8 aK = *(const bf16x8*)(wkbase + t * 4096 + offj);
                accK0[t] = __builtin_amdgcn_mfma_f32_16x16x32_bf16(aK, bs0, accK0[t], 0, 0, 0);
                accK1[t] = __builtin_amdgcn_mfma_f32_16x16x32_bf16(aK, bs1, accK1[t], 0, 0, 0);
                bf16x8 aQ = *(const bf16x8*)(wqbase + t * 4096 + offj);
                accQ0[t] = __builtin_amdgcn_mfma_f32_16x16x32_bf16(aQ, bo0, accQ0[t], 0, 0, 0);
                accQ1[t] = __builtin_amdgcn_mfma_f32_16x16x32_bf16(aQ, bo1, accQ1[t], 0, 0, 0);
            }
        }
        float d0 = 0.f, d1 = 0.f;
        const float* relA = rel + (size_t)pA * 128 + g * 4;
        const float* relB = rel + (size_t)pB * 128 + g * 4;
        #pragma unroll
        for (int t = 0; t < 8; ++t) {
            f32x4 rA = *(const f32x4*)(relA + t * 16);
            f32x4 rB = *(const f32x4*)(relB + t * 16);
            #pragma unroll
            for (int r = 0; r < 4; ++r) {
                d0 += accK0[t][r] * accQ0[t][r] * rA[r];
                d1 += accK1[t][r] * accQ1[t][r] * rB[r];
            }
        }
        d0 += __shfl_xor(d0, 16); d0 += __shfl_xor(d0, 32);
        d1 += __shfl_xor(d1, 16); d1 += __shfl_xor(d1, 32);
        if (lane < 32) {
            const float inv_s = 0.08838834764831845f;
            out[e0 + lane] = (lane < 16 ? d0 : d1) * inv_s;
        }
    }
}

extern "C" void kernel_launch(void* const* d_in, const int* in_sizes, int n_in,
                              void* d_out, int out_size, void* d_ws, size_t ws_size,
                              hipStream_t stream)
{
    const float* emb = (const float*)d_in[0];
    const float* rel = (const float*)d_in[1];
    const float* tk  = (const float*)d_in[2];
    const float* tq  = (const float*)d_in[3];
    const int*   si  = (const int*)d_in[4];
    const int*   pi  = (const int*)d_in[5];
    const int*   oi  = (const int*)d_in[6];
    float* out = (float*)d_out;

    if (ws_size >= WS_NEED_B) {
        char* ws = (char*)d_ws;
        __bf16*   embb   = (__bf16*)(ws + OFF_EMBB);
        unsigned* counts = (unsigned*)(ws + OFF_COUNTS);
        unsigned* cursor = (unsigned*)(ws + OFF_CURSOR);
        unsigned* eidx   = (unsigned*)(ws + OFF_EIDX);

        cvt_bf16<<<dim3(2048), dim3(256), 0, stream>>>(emb, embb);
        zero_counts<<<dim3(1), dim3(256), 0, stream>>>(counts);
        hist_kernel<<<dim3(SORT_BLOCKS), dim3(256), 0, stream>>>(si, counts);
        scan_kernel<<<dim3(1), dim3(256), 0, stream>>>(counts, cursor);
        scatter_kernel<<<dim3(SORT_BLOCKS), dim3(256), 0, stream>>>(si, cursor, eidx);
        sampleall_bucketed<<<dim3(GRID_BLOCKS), dim3(256), 0, stream>>>(
            embb, rel, tk, tq, si, pi, oi, eidx, out);
    } else if (ws_size >= WS_NEED_A) {
        __bf16* embb = (__bf16*)d_ws;
        cvt_bf16<<<dim3(2048), dim3(256), 0, stream>>>(emb, embb);
        sampleall_staged<<<dim3(GRID_BLOCKS), dim3(256), 0, stream>>>(
            embb, rel, tk, tq, si, pi, oi, out);
    } else {
        sampleall_fused_f32<<<dim3(512), dim3(256), 0, stream>>>(emb, rel, tk, tq, si, pi, oi, out);
    }
}

// Round 7
// 232.685 us; speedup vs baseline: 1.8102x; 1.8102x over previous
//
#include <hip/hip_runtime.h>
#include <hip/hip_bf16.h>

typedef __bf16 bf16x8 __attribute__((ext_vector_type(8)));
typedef float  f32x4  __attribute__((ext_vector_type(4)));

#define EDGES_TOTAL 1000000
#define TILE_E 16
#define TILES (EDGES_TOTAL / TILE_E)      // 62500 tiles of 16 edges
#define EMB_ELEMS 64000000ULL             // 500000*128
#define EMB_CHUNKS (EMB_ELEMS / 8)
#define WS_NEEDED (EMB_ELEMS * 2ULL)
#define GRID_BLOCKS 1280                  // 5 blocks/CU target

__device__ __forceinline__ bf16x8 load_cvt8(const float* __restrict__ p) {
    f32x4 a = *(const f32x4*)p;
    f32x4 b = *(const f32x4*)(p + 4);
    bf16x8 r;
    r[0] = (__bf16)a[0]; r[1] = (__bf16)a[1]; r[2] = (__bf16)a[2]; r[3] = (__bf16)a[3];
    r[4] = (__bf16)b[0]; r[5] = (__bf16)b[1]; r[6] = (__bf16)b[2]; r[7] = (__bf16)b[3];
    return r;
}

__device__ __forceinline__ void gload_lds16(const void* g, void* l) {
    __builtin_amdgcn_global_load_lds(
        (const __attribute__((address_space(1))) void*)g,
        (__attribute__((address_space(3))) void*)l, 16, 0, 0);
}

// ---------- Phase 0: emb f32 -> bf16 in ws ----------
// NT loads on the f32 source: the 256MB stream is read-once, keep it out of
// L3 so the freshly written embb (128MB) stays resident for the gather phase.
__global__ __launch_bounds__(256) void cvt_bf16(
    const float* __restrict__ emb, __bf16* __restrict__ dst)
{
    const size_t stride = (size_t)gridDim.x * blockDim.x;
    for (size_t i = (size_t)blockIdx.x * blockDim.x + threadIdx.x; i < EMB_CHUNKS; i += stride) {
        size_t e = i * 8;
        f32x4 a = __builtin_nontemporal_load((const f32x4*)(emb + e));
        f32x4 b = __builtin_nontemporal_load((const f32x4*)(emb + e + 4));
        bf16x8 r;
        r[0] = (__bf16)a[0]; r[1] = (__bf16)a[1]; r[2] = (__bf16)a[2]; r[3] = (__bf16)a[3];
        r[4] = (__bf16)b[0]; r[5] = (__bf16)b[1]; r[6] = (__bf16)b[2]; r[7] = (__bf16)b[3];
        *(bf16x8*)(dst + e) = r;
    }
}

// ---------- Phase 1: block-staged gather + MFMA, 16-edge tiles (R5 structure) ----------
// Block = 4 waves; wave w owns output-feature slices t = 2w, 2w+1 (W in regs).
// Per tile: 32 gathered rows (16 si + 16 oi), double-buffered 2x8KB.
__global__ __launch_bounds__(256, 5) void sampleall_staged(
    const __bf16* __restrict__ embb, const float* __restrict__ rel,
    const float* __restrict__ tokeys, const float* __restrict__ toqueries,
    const int* __restrict__ si, const int* __restrict__ pi, const int* __restrict__ oi,
    float* __restrict__ out)
{
    __shared__ __align__(16) __bf16 stage[2][32 * 128];   // 2 x 8 KiB: rows 0-15 = si, 16-31 = oi
    __shared__ float red[4][16];

    const int tid  = threadIdx.x;
    const int lane = tid & 63;
    const int wid  = tid >> 6;     // 0..3
    const int c    = lane & 15;    // edge slot / A-row / B-col
    const int g    = lane >> 4;    // k-group
    const int sub  = tid >> 4;     // 0..15: row-subgroup for staging
    const int gr   = tid & 15;     // 16B granule within row for staging

    // --- W fragments resident in registers: this wave's 2 t-slices x 4 j0 x 2 mats ---
    bf16x8 wk[2][4], wq[2][4];
    #pragma unroll
    for (int tl = 0; tl < 2; ++tl) {
        const int row = (wid * 2 + tl) * 16 + c;
        #pragma unroll
        for (int j0 = 0; j0 < 4; ++j0) {
            wk[tl][j0] = load_cvt8(tokeys    + row * 128 + j0 * 32 + g * 8);
            wq[tl][j0] = load_cvt8(toqueries + row * 128 + j0 * 32 + g * 8);
        }
    }

    // Stage a tile's 32 rows: 16 consecutive lanes cover one full 256B row ->
    // each 128B line requested by exactly one instruction. Source granule
    // pre-swizzled (gr ^ (row&7)); LDS dest linear (wave-uniform base).
    auto stage_issue = [&](int e0, int buf) {
        #pragma unroll
        for (int k = 0; k < 2; ++k) {
            const int r   = k * 16 + sub;                       // LDS row 0..31
            const int idx = k ? oi[e0 + sub] : si[e0 + sub];
            const __bf16* src = embb + (size_t)idx * 128 + (gr ^ (r & 7)) * 8;
            __bf16* dst = &stage[buf][(k * 16 + (sub & ~3)) * 128];  // wave-uniform
            gload_lds16(src, dst);
        }
    };

    auto rdfrag = [&](int buf, int p, int j0) -> bf16x8 {
        const char* base = (const char*)&stage[buf][0];
        const int off = p * 256 + ((j0 * 64 + g * 16) ^ ((p & 7) << 4));
        return *(const bf16x8*)(base + off);
    };

    int tile = (int)blockIdx.x;
    stage_issue(tile * TILE_E, 0);
    __syncthreads();                       // drains vmcnt -> buf0 ready

    int b = 0;
    for (; tile < TILES; tile += GRID_BLOCKS) {
        const int nt = tile + GRID_BLOCKS;
        if (nt < TILES) stage_issue(nt * TILE_E, b ^ 1);   // prefetch overlaps compute

        const int e0 = tile * TILE_E;
        f32x4 aK[2], aQ[2];
        #pragma unroll
        for (int tl = 0; tl < 2; ++tl) {
            aK[tl] = (f32x4){0.f, 0.f, 0.f, 0.f};
            aQ[tl] = (f32x4){0.f, 0.f, 0.f, 0.f};
        }

        #pragma unroll
        for (int j0 = 0; j0 < 4; ++j0) {
            bf16x8 bs = rdfrag(b, c,      j0);   // si rows
            bf16x8 bo = rdfrag(b, 16 + c, j0);   // oi rows
            #pragma unroll
            for (int tl = 0; tl < 2; ++tl) {
                aK[tl] = __builtin_amdgcn_mfma_f32_16x16x32_bf16(wk[tl][j0], bs, aK[tl], 0, 0, 0);
                aQ[tl] = __builtin_amdgcn_mfma_f32_16x16x32_bf16(wq[tl][j0], bo, aQ[tl], 0, 0, 0);
            }
        }

        // Epilogue: lane (g,c), slice tl holds features f = (wid*2+tl)*16 + g*4 + r.
        const int pA = pi[e0 + c];
        float d0 = 0.f;
        #pragma unroll
        for (int tl = 0; tl < 2; ++tl) {
            f32x4 rA = *(const f32x4*)(rel + (size_t)pA * 128 + (wid * 2 + tl) * 16 + g * 4);
            #pragma unroll
            for (int r = 0; r < 4; ++r)
                d0 += aK[tl][r] * aQ[tl][r] * rA[r];
        }
        d0 += __shfl_xor(d0, 16); d0 += __shfl_xor(d0, 32);   // sum over g
        if (lane < 16) red[wid][c] = d0;

        __syncthreads();   // red visible; vmcnt drained -> next buf staged
        if (tid < 16) {
            const float s = red[0][tid] + red[1][tid] + red[2][tid] + red[3][tid];
            out[e0 + tid] = s * 0.08838834764831845f;   // 1/sqrt(128)
        }
        __syncthreads();   // protect red + retired buf
        b ^= 1;
    }
}

// ---------- Fallback (no ws): R1-style f32 gathers ----------
__global__ __launch_bounds__(256, 2) void sampleall_fused_f32(
    const float* __restrict__ emb, const float* __restrict__ rel,
    const float* __restrict__ tokeys, const float* __restrict__ toqueries,
    const int* __restrict__ si, const int* __restrict__ pi, const int* __restrict__ oi,
    float* __restrict__ out)
{
    __shared__ __align__(16) __bf16 ldsW[2][128 * 128];
    const int tid = threadIdx.x;
    #pragma unroll
    for (int it = 0; it < 16; ++it) {
        int gidx = tid + it * 256;
        int m    = gidx >> 11;
        int rm   = gidx & 2047;
        int row  = rm >> 4;
        int ch   = rm & 15;
        const float* src = (m ? toqueries : tokeys) + row * 128 + ch * 8;
        bf16x8 bv = load_cvt8(src);
        int byteoff = row * 256 + ((ch * 16) ^ ((row & 7) << 4));
        *(bf16x8*)((char*)(&ldsW[m][0]) + byteoff) = bv;
    }
    __syncthreads();

    const int lane = tid & 63;
    const int wid  = tid >> 6;
    const int c    = lane & 15;
    const int g    = lane >> 4;
    const int xm   = (c & 7) << 4;
    const char* wkbase = (const char*)(&ldsW[0][0]) + c * 256;
    const char* wqbase = (const char*)(&ldsW[1][0]) + c * 256;

    const int wtotal = (int)gridDim.x * 4;
    for (int tile = (int)blockIdx.x * 4 + wid; tile < EDGES_TOTAL / 32; tile += wtotal) {
        const int e0 = tile * 32;
        const int sA = si[e0 + c], sB = si[e0 + 16 + c];
        const int oA = oi[e0 + c], oB = oi[e0 + 16 + c];
        const int pA = pi[e0 + c], pB = pi[e0 + 16 + c];
        const float* ps0 = emb + (size_t)sA * 128 + g * 8;
        const float* ps1 = emb + (size_t)sB * 128 + g * 8;
        const float* po0 = emb + (size_t)oA * 128 + g * 8;
        const float* po1 = emb + (size_t)oB * 128 + g * 8;

        f32x4 accK0[8], accK1[8], accQ0[8], accQ1[8];
        #pragma unroll
        for (int t = 0; t < 8; ++t) {
            accK0[t] = (f32x4){0.f, 0.f, 0.f, 0.f};
            accK1[t] = (f32x4){0.f, 0.f, 0.f, 0.f};
            accQ0[t] = (f32x4){0.f, 0.f, 0.f, 0.f};
            accQ1[t] = (f32x4){0.f, 0.f, 0.f, 0.f};
        }
        #pragma unroll
        for (int j0 = 0; j0 < 4; ++j0) {
            bf16x8 bs0 = load_cvt8(ps0 + j0 * 32);
            bf16x8 bs1 = load_cvt8(ps1 + j0 * 32);
            bf16x8 bo0 = load_cvt8(po0 + j0 * 32);
            bf16x8 bo1 = load_cvt8(po1 + j0 * 32);
            const int offj = ((j0 * 64 + g * 16) ^ xm);
            #pragma unroll
            for (int t = 0; t < 8; ++t) {
                bf16x8 aK = *(const bf16x8*)(wkbase + t * 4096 + offj);
                accK0[t] = __builtin_amdgcn_mfma_f32_16x16x32_bf16(aK, bs0, accK0[t], 0, 0, 0);
                accK1[t] = __builtin_amdgcn_mfma_f32_16x16x32_bf16(aK, bs1, accK1[t], 0, 0, 0);
                bf16x8 aQ = *(const bf16x8*)(wqbase + t * 4096 + offj);
                accQ0[t] = __builtin_amdgcn_mfma_f32_16x16x32_bf16(aQ, bo0, accQ0[t], 0, 0, 0);
                accQ1[t] = __builtin_amdgcn_mfma_f32_16x16x32_bf16(aQ, bo1, accQ1[t], 0, 0, 0);
            }
        }
        float d0 = 0.f, d1 = 0.f;
        const float* relA = rel + (size_t)pA * 128 + g * 4;
        const float* relB = rel + (size_t)pB * 128 + g * 4;
        #pragma unroll
        for (int t = 0; t < 8; ++t) {
            f32x4 rA = *(const f32x4*)(relA + t * 16);
            f32x4 rB = *(const f32x4*)(relB + t * 16);
            #pragma unroll
            for (int r = 0; r < 4; ++r) {
                d0 += accK0[t][r] * accQ0[t][r] * rA[r];
                d1 += accK1[t][r] * accQ1[t][r] * rB[r];
            }
        }
        d0 += __shfl_xor(d0, 16); d0 += __shfl_xor(d0, 32);
        d1 += __shfl_xor(d1, 16); d1 += __shfl_xor(d1, 32);
        if (lane < 32) {
            const float inv_s = 0.08838834764831845f;
            out[e0 + lane] = (lane < 16 ? d0 : d1) * inv_s;
        }
    }
}

extern "C" void kernel_launch(void* const* d_in, const int* in_sizes, int n_in,
                              void* d_out, int out_size, void* d_ws, size_t ws_size,
                              hipStream_t stream)
{
    const float* emb = (const float*)d_in[0];
    const float* rel = (const float*)d_in[1];
    const float* tk  = (const float*)d_in[2];
    const float* tq  = (const float*)d_in[3];
    const int*   si  = (const int*)d_in[4];
    const int*   pi  = (const int*)d_in[5];
    const int*   oi  = (const int*)d_in[6];
    float* out = (float*)d_out;

    if (ws_size >= WS_NEEDED) {
        __bf16* embb = (__bf16*)d_ws;
        cvt_bf16<<<dim3(2048), dim3(256), 0, stream>>>(emb, embb);
        sampleall_staged<<<dim3(GRID_BLOCKS), dim3(256), 0, stream>>>(
            embb, rel, tk, tq, si, pi, oi, out);
    } else {
        sampleall_fused_f32<<<dim3(512), dim3(256), 0, stream>>>(emb, rel, tk, tq, si, pi, oi, out);
    }
}